// Round 2
// baseline (211.953 us; speedup 1.0000x reference)
//
#include <hip/hip_runtime.h>

#define A_N   4096
#define EMBED 128
#define MAXO  16
#define DEG   8
#define OBSD  8
#define ORIG  18
#define KCAND (DEG * MAXO)   // 128

// ---------------------------------------------------------------------------
// Kernel A: per SOURCE agent a (block = agent, 128 threads):
//   1. encode 8 obs edges: h = relu([obj_x[o], obj_pos[o]-agent_pos[a]] @ enc_W1 + b1)
//   2. segment-sum over the 8 edges, enc = s @ enc_W2 + b2
//   3. npred[a] = argmax(enc @ mdec_Ws + mdec_bs)
//   4. elems_base[a] = enc @ mdec_Wx + mdec_bx   (288 values)
// ---------------------------------------------------------------------------
__global__ __launch_bounds__(EMBED) void enc_kernel(
    const float* __restrict__ obj_x, const float* __restrict__ obj_pos,
    const float* __restrict__ agent_pos,
    const float* __restrict__ enc_W1, const float* __restrict__ enc_b1,
    const float* __restrict__ enc_W2, const float* __restrict__ enc_b2,
    const float* __restrict__ mdec_Ws, const float* __restrict__ mdec_bs,
    const float* __restrict__ mdec_Wx, const float* __restrict__ mdec_bx,
    const int* __restrict__ obs_edge,          // (2, A_N*OBSD)
    float* __restrict__ elems_base,            // (A_N, 288)
    int* __restrict__ npred_out)               // (A_N,)
{
    const int a = blockIdx.x;
    const int t = threadIdx.x;

    __shared__ float msg[OBSD][ORIG];
    __shared__ float ssum[EMBED];
    __shared__ float encs[EMBED];
    __shared__ float logits[MAXO + 1];

    // load the 8 messages (8*18 = 144 values > 128 threads -> stride loop!)
    for (int e = t; e < OBSD * ORIG; e += EMBED) {
        const int d = e / ORIG, c = e % ORIG;
        const int o = obs_edge[A_N * OBSD + a * OBSD + d];   // row 1 = src objects
        float v;
        if (c < 16) v = obj_x[o * 16 + c];
        else        v = obj_pos[o * 2 + (c - 16)] - agent_pos[a * 2 + (c - 16)];
        msg[d][c] = v;
    }
    __syncthreads();

    // h = relu(msg @ W1 + b1), summed over the 8 edges
    {
        float w1[ORIG];
#pragma unroll
        for (int c = 0; c < ORIG; ++c) w1[c] = enc_W1[c * EMBED + t];
        const float b1 = enc_b1[t];
        float acc = 0.f;
#pragma unroll
        for (int d = 0; d < OBSD; ++d) {
            float h = b1;
#pragma unroll
            for (int c = 0; c < ORIG; ++c) h += msg[d][c] * w1[c];
            acc += fmaxf(h, 0.f);
        }
        ssum[t] = acc;
    }
    __syncthreads();

    // enc = s @ W2 + b2
    {
        float e = enc_b2[t];
        for (int c = 0; c < EMBED; ++c) e += ssum[c] * enc_W2[c * EMBED + t];
        encs[t] = e;
    }
    __syncthreads();

    // npred = argmax(enc @ mdec_Ws + bs)   (first max, like jnp.argmax)
    if (t < MAXO + 1) {
        float lg = mdec_bs[t];
        for (int c = 0; c < EMBED; ++c) lg += encs[c] * mdec_Ws[c * (MAXO + 1) + t];
        logits[t] = lg;
    }
    __syncthreads();
    if (t == 0) {
        int best = 0; float bv = logits[0];
        for (int q = 1; q <= MAXO; ++q) if (logits[q] > bv) { bv = logits[q]; best = q; }
        npred_out[a] = best;
    }

    // elems_base = enc @ mdec_Wx + bx  (288 outputs over 128 threads)
    for (int e = t; e < MAXO * ORIG; e += EMBED) {
        float v = mdec_bx[e];
        for (int c = 0; c < EMBED; ++c) v += encs[c] * mdec_Wx[c * (MAXO * ORIG) + e];
        elems_base[(size_t)a * (MAXO * ORIG) + e] = v;
    }
}

// ---------------------------------------------------------------------------
// Kernel B: per TARGET agent i (block = agent, 128 threads = 128 candidates):
//   gather cands from 8 neighbors, add relpos, valid = m < npred[j]
//   dedup (pairwise dist < 0.02 vs earlier valid), cap kept at 15 (cumsum)
//   hsum = sum_k keep * relu(cand @ menc_W1 + b1);  merged = hsum @ menc_W2 + b2
//   n2 = argmax(merged @ dec_Ws + bs); decoded = (merged @ dec_Wx + bx) * mask
// ---------------------------------------------------------------------------
__global__ __launch_bounds__(EMBED) void merge_kernel(
    const float* __restrict__ agent_pos,
    const float* __restrict__ menc_W1, const float* __restrict__ menc_b1,
    const float* __restrict__ menc_W2, const float* __restrict__ menc_b2,
    const float* __restrict__ dec_Ws, const float* __restrict__ dec_bs,
    const float* __restrict__ dec_Wx, const float* __restrict__ dec_bx,
    const int* __restrict__ comm_edge,         // (2, A_N*DEG) row0=src j, row1=tgt i
    const float* __restrict__ elems_base, const int* __restrict__ npred,
    float* __restrict__ out_dec, float* __restrict__ out_batch,
    float* __restrict__ out_mask)
{
    const int i = blockIdx.x;
    const int t = threadIdx.x;

    __shared__ float cand[KCAND][ORIG];
    __shared__ float px[KCAND], py[KCAND];
    __shared__ int   vld[KCAND], keep[KCAND];
    __shared__ float hsum[EMBED];
    __shared__ float mg[EMBED];
    __shared__ float lg2[MAXO + 1];
    __shared__ int   n2s;
    __shared__ int   wave0cnt;

    // ---- gather candidate t ----
    {
        const int d = t >> 4;       // neighbor slot 0..7
        const int m = t & 15;       // element slot 0..15
        const int e = i * DEG + d;
        const int j  = comm_edge[e];                 // src
        const int ii = comm_edge[A_N * DEG + e];     // tgt
        const float rx = agent_pos[j * 2 + 0] - agent_pos[ii * 2 + 0];
        const float ry = agent_pos[j * 2 + 1] - agent_pos[ii * 2 + 1];
        const float* eb = elems_base + (size_t)j * (MAXO * ORIG) + m * ORIG;
#pragma unroll
        for (int c = 0; c < 16; ++c) cand[t][c] = eb[c];
        const float qx = eb[16] + rx, qy = eb[17] + ry;
        cand[t][16] = qx; cand[t][17] = qy;
        px[t] = qx; py[t] = qy;
        vld[t] = (m < npred[j]) ? 1 : 0;
    }
    __syncthreads();

    // ---- dedup + cap-at-15 ----
    {
        int dup = 0;
        const float qx = px[t], qy = py[t];
        for (int k1 = 0; k1 < KCAND; ++k1) {
            if (k1 < t && vld[k1]) {
                const float dx = px[k1] - qx, dy = py[k1] - qy;
                if (sqrtf(dx * dx + dy * dy) < 0.02f) dup = 1;
            }
        }
        int kp = (vld[t] && !dup) ? 1 : 0;
        const unsigned long long bal = __ballot(kp);
        const int lane = t & 63;
        int cnt = (int)__popcll(bal << (63 - lane));   // inclusive prefix in wave
        if (t == 0) wave0cnt = 0;
        __syncthreads();
        if (t < 64 && lane == 0) wave0cnt = (int)__popcll(bal);
        __syncthreads();
        if (t >= 64) cnt += wave0cnt;
        kp = (kp && cnt <= MAXO - 1) ? 1 : 0;
        keep[t] = kp;
    }
    __syncthreads();

    // ---- hsum[t] = sum over kept k of relu(cand[k] . menc_W1[:,t] + b1[t]) ----
    {
        float w1[ORIG];
#pragma unroll
        for (int c = 0; c < ORIG; ++c) w1[c] = menc_W1[c * EMBED + t];
        const float b1t = menc_b1[t];
        float hs = 0.f;
        for (int k = 0; k < KCAND; ++k) {
            if (keep[k]) {
                float h = b1t;
#pragma unroll
                for (int c = 0; c < ORIG; ++c) h += cand[k][c] * w1[c];
                hs += fmaxf(h, 0.f);
            }
        }
        hsum[t] = hs;
    }
    __syncthreads();

    // ---- merged = hsum @ menc_W2 + b2 ----
    {
        float mv = menc_b2[t];
        for (int c = 0; c < EMBED; ++c) mv += hsum[c] * menc_W2[c * EMBED + t];
        mg[t] = mv;
    }
    __syncthreads();

    // ---- n2 = argmax(merged @ dec_Ws + bs) ----
    if (t < MAXO + 1) {
        float lgv = dec_bs[t];
        for (int c = 0; c < EMBED; ++c) lgv += mg[c] * dec_Ws[c * (MAXO + 1) + t];
        lg2[t] = lgv;
    }
    __syncthreads();
    if (t == 0) {
        int best = 0; float bv = lg2[0];
        for (int q = 1; q <= MAXO; ++q) if (lg2[q] > bv) { bv = lg2[q]; best = q; }
        n2s = best;
    }
    __syncthreads();
    const int n2 = n2s;

    // ---- decoded (masked), batch, mask ----
    for (int e = t; e < MAXO * ORIG; e += EMBED) {
        const int m = e / ORIG;
        float v = 0.f;
        if (m < n2) {
            v = dec_bx[e];
            for (int c = 0; c < EMBED; ++c) v += mg[c] * dec_Wx[c * (MAXO * ORIG) + e];
        }
        out_dec[(size_t)i * (MAXO * ORIG) + e] = v;
    }
    if (t < MAXO) {
        out_batch[i * MAXO + t] = (float)i;
        out_mask[i * MAXO + t]  = (t < n2) ? 1.f : 0.f;
    }
}

extern "C" void kernel_launch(void* const* d_in, const int* in_sizes, int n_in,
                              void* d_out, int out_size, void* d_ws, size_t ws_size,
                              hipStream_t stream)
{
    const float* obj_x     = (const float*)d_in[0];
    const float* obj_pos   = (const float*)d_in[1];
    const float* agent_pos = (const float*)d_in[2];
    const float* enc_W1    = (const float*)d_in[3];
    const float* enc_b1    = (const float*)d_in[4];
    const float* enc_W2    = (const float*)d_in[5];
    const float* enc_b2    = (const float*)d_in[6];
    const float* mdec_Ws   = (const float*)d_in[7];
    const float* mdec_bs   = (const float*)d_in[8];
    const float* mdec_Wx   = (const float*)d_in[9];
    const float* mdec_bx   = (const float*)d_in[10];
    const float* menc_W1   = (const float*)d_in[11];
    const float* menc_b1   = (const float*)d_in[12];
    const float* menc_W2   = (const float*)d_in[13];
    const float* menc_b2   = (const float*)d_in[14];
    const float* dec_Ws    = (const float*)d_in[15];
    const float* dec_bs    = (const float*)d_in[16];
    const float* dec_Wx    = (const float*)d_in[17];
    const float* dec_bx    = (const float*)d_in[18];
    const int*   obs_edge  = (const int*)d_in[19];
    const int*   comm_edge = (const int*)d_in[20];

    float* elems_base = (float*)d_ws;                                  // 4096*288 f32
    int*   npred      = (int*)((char*)d_ws + (size_t)A_N * MAXO * ORIG * sizeof(float));

    float* out_dec   = (float*)d_out;                                  // 4096*288
    float* out_batch = out_dec + (size_t)A_N * MAXO * ORIG;            // 4096*16
    float* out_mask  = out_batch + (size_t)A_N * MAXO;                 // 4096*16

    enc_kernel<<<A_N, EMBED, 0, stream>>>(
        obj_x, obj_pos, agent_pos, enc_W1, enc_b1, enc_W2, enc_b2,
        mdec_Ws, mdec_bs, mdec_Wx, mdec_bx, obs_edge, elems_base, npred);

    merge_kernel<<<A_N, EMBED, 0, stream>>>(
        agent_pos, menc_W1, menc_b1, menc_W2, menc_b2,
        dec_Ws, dec_bs, dec_Wx, dec_bx, comm_edge,
        elems_base, npred, out_dec, out_batch, out_mask);
}